// Round 1
// baseline (320.081 us; speedup 1.0000x reference)
//
#include <hip/hip_runtime.h>

typedef __bf16 bf16;
typedef bf16 bf16x8 __attribute__((ext_vector_type(8)));
typedef bf16 bf16x4 __attribute__((ext_vector_type(4)));
typedef float f32x4 __attribute__((ext_vector_type(4)));

#define SEQ 4096
#define SQQ 1024
#define NH  6
#define HD  64

// -------------------------------------------------------------------------
// K1: QKV GEMM (fp32): X[16384x192] @ W[192x1152] + b
// epilogue: Q -> bf16 [m][384]; K -> bf16 [bh][s][64]; V -> bf16 TRANSPOSED [bh][64][s]
// tile 128x128, BK=16, 256 thr, 8x8 per thread
// n-blocks align with q/k/v boundaries (384 = 3*128) -> c3 uniform per block
// -------------------------------------------------------------------------
__global__ __launch_bounds__(256) void k_qkv(
    const float* __restrict__ X, const float* __restrict__ W,
    const float* __restrict__ bias,
    bf16* __restrict__ Qb, bf16* __restrict__ Kb, bf16* __restrict__ Vt)
{
  __shared__ __attribute__((aligned(16))) float As[16 * 132]; // [k][m] transposed
  __shared__ __attribute__((aligned(16))) float Bs[16 * 132]; // [k][n]
  const int tid = threadIdx.x;
  const int tx = tid & 15, ty = tid >> 4;
  const int m0 = blockIdx.x * 128;
  const int n0 = blockIdx.y * 128;

  float acc[8][8] = {};

  for (int kt = 0; kt < 12; ++kt) {
    const int k0 = kt * 16;
#pragma unroll
    for (int cc = 0; cc < 2; ++cc) {
      int ch = tid * 2 + cc;
      int arow = ch >> 2, ac4 = ch & 3;
      f32x4 av = *(const f32x4*)&X[(size_t)(m0 + arow) * 192 + k0 + ac4 * 4];
#pragma unroll
      for (int e = 0; e < 4; ++e) As[(ac4 * 4 + e) * 132 + arow] = av[e];
      int brow = ch >> 5, bc4 = ch & 31;
      f32x4 bv = *(const f32x4*)&W[(size_t)(k0 + brow) * 1152 + n0 + bc4 * 4];
      *(f32x4*)&Bs[brow * 132 + bc4 * 4] = bv;
    }
    __syncthreads();
#pragma unroll
    for (int kk = 0; kk < 16; ++kk) {
      f32x4 a0 = *(const f32x4*)&As[kk * 132 + ty * 8];
      f32x4 a1 = *(const f32x4*)&As[kk * 132 + ty * 8 + 4];
      f32x4 b0 = *(const f32x4*)&Bs[kk * 132 + tx * 4];
      f32x4 b1 = *(const f32x4*)&Bs[kk * 132 + 64 + tx * 4];
      float a[8] = {a0[0], a0[1], a0[2], a0[3], a1[0], a1[1], a1[2], a1[3]};
      float b[8] = {b0[0], b0[1], b0[2], b0[3], b1[0], b1[1], b1[2], b1[3]};
#pragma unroll
      for (int i = 0; i < 8; ++i)
#pragma unroll
        for (int j = 0; j < 8; ++j)
          acc[i][j] = fmaf(a[i], b[j], acc[i][j]);
    }
    __syncthreads();
  }

  const f32x4 bias0 = *(const f32x4*)&bias[n0 + tx * 4];
  const f32x4 bias1 = *(const f32x4*)&bias[n0 + 64 + tx * 4];
  const int c3 = n0 / 384;          // 0=q, 1=k, 2=v (uniform per block)
  const int nb = n0 - c3 * 384;
  const int b  = m0 >> 12;

  if (c3 == 0) {
#pragma unroll
    for (int i = 0; i < 8; ++i) {
      int m = m0 + ty * 8 + i;
      bf16x4 p0, p1;
#pragma unroll
      for (int jj = 0; jj < 4; ++jj) {
        p0[jj] = (bf16)(acc[i][jj] + bias0[jj]);
        p1[jj] = (bf16)(acc[i][4 + jj] + bias1[jj]);
      }
      *(bf16x4*)&Qb[(size_t)m * 384 + nb + tx * 4] = p0;
      *(bf16x4*)&Qb[(size_t)m * 384 + nb + 64 + tx * 4] = p1;
    }
  } else if (c3 == 1) {
#pragma unroll
    for (int g = 0; g < 2; ++g) {
      int rem = nb + tx * 4 + g * 64;
      int h = rem >> 6, d = rem & 63;
      const f32x4 bg = g ? bias1 : bias0;
      size_t base = (size_t)(b * NH + h) * SEQ * HD + d;
#pragma unroll
      for (int i = 0; i < 8; ++i) {
        int s = (m0 & 4095) + ty * 8 + i;
        bf16x4 pk;
#pragma unroll
        for (int jj = 0; jj < 4; ++jj) pk[jj] = (bf16)(acc[i][g * 4 + jj] + bg[jj]);
        *(bf16x4*)&Kb[base + (size_t)s * HD] = pk;
      }
    }
  } else {
    int s0 = (m0 & 4095) + ty * 8;
#pragma unroll
    for (int j = 0; j < 8; ++j) {
      int rem = nb + (j >> 2) * 64 + tx * 4 + (j & 3);
      int h = rem >> 6, d = rem & 63;
      float bj = (j < 4) ? bias0[j & 3] : bias1[j & 3];
      bf16x8 pk;
#pragma unroll
      for (int i = 0; i < 8; ++i) pk[i] = (bf16)(acc[i][j] + bj);
      *(bf16x8*)&Vt[((size_t)(b * NH + h) * HD + d) * SEQ + s0] = pk;
    }
  }
}

// -------------------------------------------------------------------------
// K2: 2x2 max-pool on Q, fold in scale 1/8 (exact power of 2 in bf16)
// out Qp: [bh][qq=hq*32+wq][d]
// -------------------------------------------------------------------------
__global__ __launch_bounds__(256) void k_pool(const bf16* __restrict__ Qb,
                                              bf16* __restrict__ Qp)
{
  int o = blockIdx.x * 256 + threadIdx.x;      // 1572864 total
  int d  = o & 63;
  int qq = (o >> 6) & 1023;
  int bh = o >> 16;
  int b = bh / NH, h = bh - b * NH;
  int hq = qq >> 5, wq = qq & 31;
  const bf16* p = Qb + (size_t)(b * 4096 + hq * 128 + wq * 2) * 384 + h * 64 + d;
  float v0 = (float)p[0];
  float v1 = (float)p[384];
  float v2 = (float)p[64 * 384];
  float v3 = (float)p[64 * 384 + 384];
  float mx = fmaxf(fmaxf(v0, v1), fmaxf(v2, v3));
  Qp[o] = (bf16)(mx * 0.125f);
}

// -------------------------------------------------------------------------
// K3: flash attention, mfma_f32_16x16x32_bf16.
// grid (bh=24, qt=32) -> same-bh blocks land on one XCD (24*qt % 8 == 0).
// 128 thr = 2 waves, 16 q-rows each; K-tile = 64. K/V staged to LDS with
// +8 bf16 pad (stride 72): staging writes AND frag reads are slot-uniform.
// P: C-layout -> A-layout via per-wave LDS round-trip (f32, stride 68).
// A-frag: A[m=l16][k=quad*8+j]; B-frag: B[k=quad*8+j][n=l16];
// C/D:    row=quad*4+r, col=l16  (m89/m91-verified layouts).
// -------------------------------------------------------------------------
__global__ __launch_bounds__(128) void k_attn(
    const bf16* __restrict__ Qp, const bf16* __restrict__ Kb,
    const bf16* __restrict__ Vt, float* __restrict__ Ob)
{
  __shared__ __attribute__((aligned(16))) bf16 Ks[64 * 72];   // [kpos][d]
  __shared__ __attribute__((aligned(16))) bf16 Vs[64 * 72];   // [d][kpos]
  __shared__ __attribute__((aligned(16))) float Ps[2][16 * 68];

  const int tid = threadIdx.x;
  const int wv = tid >> 6, lane = tid & 63;
  const int quad = lane >> 4, l16 = lane & 15;
  const int bh = blockIdx.x, qt = blockIdx.y;
  const int q0 = qt * 32 + wv * 16;

  const bf16* Qbh = Qp + (size_t)bh * SQQ * HD;
  const bf16* Kbh = Kb + (size_t)bh * SEQ * HD;
  const bf16* Vbh = Vt + (size_t)bh * HD * SEQ;

  bf16x8 aQ0 = *(const bf16x8*)&Qbh[(q0 + l16) * HD + quad * 8];
  bf16x8 aQ1 = *(const bf16x8*)&Qbh[(q0 + l16) * HD + 32 + quad * 8];

  f32x4 accO[4];
  float m_i[4], l_i[4];
#pragma unroll
  for (int nt = 0; nt < 4; ++nt) accO[nt] = (f32x4){0.f, 0.f, 0.f, 0.f};
#pragma unroll
  for (int r = 0; r < 4; ++r) { m_i[r] = -3.0e38f; l_i[r] = 0.f; }

  float* PsW = Ps[wv];

  for (int kt = 0; kt < 64; ++kt) {
    __syncthreads();   // protect previous iteration's K/V reads
#pragma unroll
    for (int c = 0; c < 4; ++c) {
      int idx = c * 128 + tid;               // 512 chunks of 8 bf16
      int row = idx >> 3, c8 = idx & 7;
      *(bf16x8*)&Ks[row * 72 + c8 * 8] =
          *(const bf16x8*)&Kbh[(size_t)(kt * 64 + row) * HD + c8 * 8];
      *(bf16x8*)&Vs[row * 72 + c8 * 8] =
          *(const bf16x8*)&Vbh[(size_t)row * SEQ + kt * 64 + c8 * 8];
    }
    __syncthreads();

    // S = Q @ K^T  (scale already folded into Qp)
    f32x4 Sf[4];
#pragma unroll
    for (int nt = 0; nt < 4; ++nt) {
      f32x4 c = {0.f, 0.f, 0.f, 0.f};
      bf16x8 bK0 = *(const bf16x8*)&Ks[(nt * 16 + l16) * 72 + quad * 8];
      bf16x8 bK1 = *(const bf16x8*)&Ks[(nt * 16 + l16) * 72 + 32 + quad * 8];
      c = __builtin_amdgcn_mfma_f32_16x16x32_bf16(aQ0, bK0, c, 0, 0, 0);
      c = __builtin_amdgcn_mfma_f32_16x16x32_bf16(aQ1, bK1, c, 0, 0, 0);
      Sf[nt] = c;
    }

    // online softmax (row r lives at quad*4+r; reduce across 16 lanes of quad)
    float alpha[4];
#pragma unroll
    for (int r = 0; r < 4; ++r) {
      float mx = fmaxf(fmaxf(Sf[0][r], Sf[1][r]), fmaxf(Sf[2][r], Sf[3][r]));
#pragma unroll
      for (int off = 1; off < 16; off <<= 1) mx = fmaxf(mx, __shfl_xor(mx, off));
      float mnew = fmaxf(m_i[r], mx);
      alpha[r] = __expf(m_i[r] - mnew);
      float rs = 0.f;
#pragma unroll
      for (int nt = 0; nt < 4; ++nt) {
        float p = __expf(Sf[nt][r] - mnew);
        Sf[nt][r] = p;
        rs += p;
      }
#pragma unroll
      for (int off = 1; off < 16; off <<= 1) rs += __shfl_xor(rs, off);
      l_i[r] = l_i[r] * alpha[r] + rs;
      m_i[r] = mnew;
    }

    // P: C-layout -> LDS (per-wave, in-order DS pipe + waitcnt)
#pragma unroll
    for (int nt = 0; nt < 4; ++nt)
#pragma unroll
      for (int r = 0; r < 4; ++r)
        PsW[(quad * 4 + r) * 68 + nt * 16 + l16] = Sf[nt][r];

    __asm__ volatile("s_waitcnt lgkmcnt(0)" ::: "memory");

#pragma unroll
    for (int nt = 0; nt < 4; ++nt)
#pragma unroll
      for (int r = 0; r < 4; ++r)
        accO[nt][r] *= alpha[r];

    // O += P @ V
#pragma unroll
    for (int ks = 0; ks < 2; ++ks) {
      f32x4 p0 = *(const f32x4*)&PsW[l16 * 68 + ks * 32 + quad * 8];
      f32x4 p1 = *(const f32x4*)&PsW[l16 * 68 + ks * 32 + quad * 8 + 4];
      bf16x8 aP;
#pragma unroll
      for (int jj = 0; jj < 4; ++jj) {
        aP[jj]     = (bf16)p0[jj];
        aP[4 + jj] = (bf16)p1[jj];
      }
#pragma unroll
      for (int nt = 0; nt < 4; ++nt) {
        bf16x8 bV = *(const bf16x8*)&Vs[(nt * 16 + l16) * 72 + ks * 32 + quad * 8];
        accO[nt] = __builtin_amdgcn_mfma_f32_16x16x32_bf16(aP, bV, accO[nt], 0, 0, 0);
      }
    }
  }

  // epilogue: O /= l, write [b][q][h][d] (proj-friendly rows of 384)
  const int b = bh / NH, h = bh - b * NH;
#pragma unroll
  for (int r = 0; r < 4; ++r) {
    float inv = 1.0f / l_i[r];
    int q = q0 + quad * 4 + r;
#pragma unroll
    for (int nt = 0; nt < 4; ++nt) {
      int d = nt * 16 + l16;
      Ob[(((size_t)b * SQQ + q) * NH + h) * HD + d] = accO[nt][r] * inv;
    }
  }
}

// -------------------------------------------------------------------------
// K4: proj GEMM (fp32): O[4096x384] @ Wp[384x384] + b -> out
// tile 64x128, BK=16, 256 thr, 4x8 per thread
// -------------------------------------------------------------------------
__global__ __launch_bounds__(256) void k_proj(
    const float* __restrict__ A, const float* __restrict__ W,
    const float* __restrict__ bias, float* __restrict__ out)
{
  __shared__ __attribute__((aligned(16))) float As[16 * 68];   // [k][m]
  __shared__ __attribute__((aligned(16))) float Bs[16 * 132];  // [k][n]
  const int tid = threadIdx.x;
  const int tx = tid & 15, ty = tid >> 4;
  const int m0 = blockIdx.x * 64;
  const int n0 = blockIdx.y * 128;
  float acc[4][8] = {};

  for (int kt = 0; kt < 24; ++kt) {
    const int k0 = kt * 16;
    {
      int arow = tid >> 2, ac4 = tid & 3;
      f32x4 av = *(const f32x4*)&A[(size_t)(m0 + arow) * 384 + k0 + ac4 * 4];
#pragma unroll
      for (int e = 0; e < 4; ++e) As[(ac4 * 4 + e) * 68 + arow] = av[e];
#pragma unroll
      for (int cc = 0; cc < 2; ++cc) {
        int ch = tid * 2 + cc;
        int brow = ch >> 5, bc4 = ch & 31;
        f32x4 bv = *(const f32x4*)&W[(size_t)(k0 + brow) * 384 + n0 + bc4 * 4];
        *(f32x4*)&Bs[brow * 132 + bc4 * 4] = bv;
      }
    }
    __syncthreads();
#pragma unroll
    for (int kk = 0; kk < 16; ++kk) {
      f32x4 a  = *(const f32x4*)&As[kk * 68 + ty * 4];
      f32x4 b0 = *(const f32x4*)&Bs[kk * 132 + tx * 4];
      f32x4 b1 = *(const f32x4*)&Bs[kk * 132 + 64 + tx * 4];
#pragma unroll
      for (int i = 0; i < 4; ++i)
#pragma unroll
        for (int j = 0; j < 4; ++j) {
          acc[i][j]     = fmaf(a[i], b0[j], acc[i][j]);
          acc[i][4 + j] = fmaf(a[i], b1[j], acc[i][4 + j]);
        }
    }
    __syncthreads();
  }

  const f32x4 pb0 = *(const f32x4*)&bias[n0 + tx * 4];
  const f32x4 pb1 = *(const f32x4*)&bias[n0 + 64 + tx * 4];
#pragma unroll
  for (int i = 0; i < 4; ++i) {
    int m = m0 + ty * 4 + i;
    f32x4 o0, o1;
#pragma unroll
    for (int jj = 0; jj < 4; ++jj) {
      o0[jj] = acc[i][jj] + pb0[jj];
      o1[jj] = acc[i][4 + jj] + pb1[jj];
    }
    *(f32x4*)&out[(size_t)m * 384 + n0 + tx * 4] = o0;
    *(f32x4*)&out[(size_t)m * 384 + n0 + 64 + tx * 4] = o1;
  }
}

// -------------------------------------------------------------------------
// ws layout (bytes):
//   Qb  bf16 16384*384   @ 0          (12582912)
//   Kb  bf16 24*4096*64  @ 12582912   (12582912)
//   Vt  bf16 24*64*4096  @ 25165824   (12582912)  [transposed per (b,h)]
//   Qp  bf16 24*1024*64  @ 37748736   ( 3145728)
//   Ob  f32  4096*384    @ 40894464   ( 6291456)
// total 47185920 B
// -------------------------------------------------------------------------
extern "C" void kernel_launch(void* const* d_in, const int* in_sizes, int n_in,
                              void* d_out, int out_size, void* d_ws, size_t ws_size,
                              hipStream_t stream)
{
  (void)in_sizes; (void)n_in; (void)out_size; (void)ws_size;
  const float* X  = (const float*)d_in[0];
  const float* Wq = (const float*)d_in[1];
  const float* qb = (const float*)d_in[2];
  const float* Wp = (const float*)d_in[3];
  const float* pb = (const float*)d_in[4];
  float* out = (float*)d_out;

  char* ws = (char*)d_ws;
  bf16*  Qb = (bf16*)(ws);
  bf16*  Kb = (bf16*)(ws + 12582912);
  bf16*  Vt = (bf16*)(ws + 2 * 12582912);
  bf16*  Qp = (bf16*)(ws + 3 * 12582912);
  float* Ob = (float*)(ws + 3 * 12582912 + 3145728);

  k_qkv <<<dim3(128, 9), 256, 0, stream>>>(X, Wq, qb, Qb, Kb, Vt);
  k_pool<<<dim3(6144),   256, 0, stream>>>(Qb, Qp);
  k_attn<<<dim3(24, 32), 128, 0, stream>>>(Qp, Kb, Vt, Ob);
  k_proj<<<dim3(64, 3),  256, 0, stream>>>(Ob, Wp, pb, out);
}

// Round 2
// 168.605 us; speedup vs baseline: 1.8984x; 1.8984x over previous
//
#include <hip/hip_runtime.h>

typedef __bf16 bf16;
typedef bf16 bf16x8 __attribute__((ext_vector_type(8)));
typedef bf16 bf16x4 __attribute__((ext_vector_type(4)));
typedef float f32x4 __attribute__((ext_vector_type(4)));

#define SEQ 4096
#define SQQ 1024
#define NH  6
#define HD  64

#define MFMA16 __builtin_amdgcn_mfma_f32_16x16x32_bf16

typedef const __attribute__((address_space(1))) void gvoid_t;
typedef __attribute__((address_space(3))) void svoid_t;

__device__ __forceinline__ void gload16(const bf16* g, bf16* l) {
  __builtin_amdgcn_global_load_lds((gvoid_t*)g, (svoid_t*)l, 16, 0, 0);
}

// -------------------------------------------------------------------------
// K0: weight prep — transpose+convert Wq [192][1152] -> Wqt bf16 [1152][192],
//     Wp [384][384] -> Wpt bf16 [384 n][384 k]
// -------------------------------------------------------------------------
__global__ __launch_bounds__(256) void k_prep(
    const float* __restrict__ Wq, const float* __restrict__ Wp,
    bf16* __restrict__ Wqt, bf16* __restrict__ Wpt)
{
  int i = blockIdx.x * 256 + threadIdx.x;
  if (i < 1152 * 192) {
    int n = i / 192, k = i - n * 192;
    Wqt[i] = (bf16)Wq[k * 1152 + n];
  } else {
    int j = i - 1152 * 192;
    if (j < 384 * 384) {
      int n = j / 384, k = j - n * 384;
      Wpt[j] = (bf16)Wp[k * 384 + n];
    }
  }
}

// -------------------------------------------------------------------------
// K1: QKV GEMM, bf16 MFMA. X[16384x192] (f32, converted in staging) @
// Wqt[1152 n][192 k] + bias. Block 256 thr = 4 waves (2x2), tile 128x128,
// BK=32, 6 k-chunks. Epilogue: V-blocks normal orientation (D[m=s][n]),
// Q/K-blocks swapped (D[n][m]) so all scatter stores are b64 along 4
// consecutive elements. 384 = 3*128 -> c3 uniform per block.
// -------------------------------------------------------------------------
__global__ __launch_bounds__(256) void k_qkv(
    const float* __restrict__ X, const bf16* __restrict__ Wt,
    const float* __restrict__ bias,
    bf16* __restrict__ Qb, bf16* __restrict__ Kb, bf16* __restrict__ Vt)
{
  __shared__ __attribute__((aligned(16))) bf16 Xs[128 * 40];
  __shared__ __attribute__((aligned(16))) bf16 Ws[128 * 40];
  const int tid = threadIdx.x;
  const int w = tid >> 6, lane = tid & 63, quad = lane >> 4, l16 = lane & 15;
  const int wm = w & 1, wn = w >> 1;
  const int m0 = blockIdx.x * 128, n0 = blockIdx.y * 128;
  const int c3 = n0 / 384, nb = n0 - c3 * 384, b = m0 >> 12;
  const int row2 = tid >> 1, koff = (tid & 1) * 16;

  f32x4 acc[4][4] = {};

  for (int kc = 0; kc < 6; ++kc) {
    const int k0 = kc * 32;
    f32x4 xv[4];
#pragma unroll
    for (int e = 0; e < 4; ++e)
      xv[e] = *(const f32x4*)&X[(size_t)(m0 + row2) * 192 + k0 + koff + e * 4];
    bf16x8 wv[2];
#pragma unroll
    for (int e = 0; e < 2; ++e)
      wv[e] = *(const bf16x8*)&Wt[(size_t)(n0 + row2) * 192 + k0 + koff + e * 8];
    __syncthreads();
#pragma unroll
    for (int e = 0; e < 2; ++e) {
      bf16x8 hx;
#pragma unroll
      for (int u = 0; u < 4; ++u) {
        hx[u]     = (bf16)xv[e * 2][u];
        hx[4 + u] = (bf16)xv[e * 2 + 1][u];
      }
      *(bf16x8*)&Xs[row2 * 40 + koff + e * 8] = hx;
      *(bf16x8*)&Ws[row2 * 40 + koff + e * 8] = wv[e];
    }
    __syncthreads();
    bf16x8 af[4], bw[4];
#pragma unroll
    for (int t = 0; t < 4; ++t) {
      af[t] = *(const bf16x8*)&Xs[(wm * 64 + t * 16 + l16) * 40 + quad * 8];
      bw[t] = *(const bf16x8*)&Ws[(wn * 64 + t * 16 + l16) * 40 + quad * 8];
    }
    if (c3 == 2) {
#pragma unroll
      for (int mt = 0; mt < 4; ++mt)
#pragma unroll
        for (int nt = 0; nt < 4; ++nt)
          acc[mt][nt] = MFMA16(af[mt], bw[nt], acc[mt][nt], 0, 0, 0);
    } else {
#pragma unroll
      for (int mt = 0; mt < 4; ++mt)
#pragma unroll
        for (int nt = 0; nt < 4; ++nt)
          acc[mt][nt] = MFMA16(bw[nt], af[mt], acc[mt][nt], 0, 0, 0);
    }
  }

  if (c3 == 2) {
    // normal: D row = m = s (quad*4+r), col = n = d-col (l16). Store V^T[d][s].
    float bn[4];
#pragma unroll
    for (int nt = 0; nt < 4; ++nt) bn[nt] = bias[n0 + wn * 64 + nt * 16 + l16];
#pragma unroll
    for (int mt = 0; mt < 4; ++mt) {
      int sb = (m0 & 4095) + wm * 64 + mt * 16 + quad * 4;
#pragma unroll
      for (int nt = 0; nt < 4; ++nt) {
        int dcol = nb + wn * 64 + nt * 16 + l16;
        int h = dcol >> 6, dd = dcol & 63;
        bf16x4 pv;
#pragma unroll
        for (int r = 0; r < 4; ++r) pv[r] = (bf16)(acc[mt][nt][r] + bn[nt]);
        *(bf16x4*)&Vt[((size_t)(b * NH + h) * HD + dd) * SEQ + sb] = pv;
      }
    }
  } else {
    // swapped: D row = n (quad*4+r), col = m (l16). 4 consecutive n per lane.
    f32x4 bv[4];
#pragma unroll
    for (int nt = 0; nt < 4; ++nt)
      bv[nt] = *(const f32x4*)&bias[n0 + wn * 64 + nt * 16 + quad * 4];
    if (c3 == 0) {
#pragma unroll
      for (int mt = 0; mt < 4; ++mt) {
        int m = m0 + wm * 64 + mt * 16 + l16;
#pragma unroll
        for (int nt = 0; nt < 4; ++nt) {
          bf16x4 pv;
#pragma unroll
          for (int r = 0; r < 4; ++r) pv[r] = (bf16)(acc[mt][nt][r] + bv[nt][r]);
          *(bf16x4*)&Qb[(size_t)m * 384 + nb + wn * 64 + nt * 16 + quad * 4] = pv;
        }
      }
    } else {
#pragma unroll
      for (int mt = 0; mt < 4; ++mt) {
        int s = (m0 & 4095) + wm * 64 + mt * 16 + l16;
#pragma unroll
        for (int nt = 0; nt < 4; ++nt) {
          int ncol = nb + wn * 64 + nt * 16 + quad * 4;
          int h = ncol >> 6, dd = ncol & 63;
          bf16x4 pv;
#pragma unroll
          for (int r = 0; r < 4; ++r) pv[r] = (bf16)(acc[mt][nt][r] + bv[nt][r]);
          *(bf16x4*)&Kb[((size_t)(b * NH + h) * SEQ + s) * HD + dd] = pv;
        }
      }
    }
  }
}

// -------------------------------------------------------------------------
// K2: 2x2 max-pool on Q; fold scale (1/8)*log2(e) so attention uses exp2.
// -------------------------------------------------------------------------
__global__ __launch_bounds__(256) void k_pool(const bf16* __restrict__ Qb,
                                              bf16* __restrict__ Qp)
{
  int o = blockIdx.x * 256 + threadIdx.x;
  int d = o & 63;
  int qq = (o >> 6) & 1023;
  int bh = o >> 16;
  int b = bh / NH, h = bh - b * NH;
  int hq = qq >> 5, wq = qq & 31;
  const bf16* p = Qb + (size_t)(b * 4096 + hq * 128 + wq * 2) * 384 + h * 64 + d;
  float v0 = (float)p[0];
  float v1 = (float)p[384];
  float v2 = (float)p[64 * 384];
  float v3 = (float)p[64 * 384 + 384];
  float mx = fmaxf(fmaxf(v0, v1), fmaxf(v2, v3));
  Qp[o] = (bf16)(mx * 0.180336880111f);   // 0.125 * log2(e)
}

// -------------------------------------------------------------------------
// K3: attention, S^T formulation, no max-stabilization (|logit|<~13, safe).
// Grid (bh=24, qblk=8, ksplit=4); 256 thr = 4 waves, 32 q/wave, K-tile 64,
// 16 iters/block. K/V staged unpadded via global_load_lds w/ XOR-swizzled
// source columns (conflict-free b128 frag reads). P round-trip per wave:
// 8 b64 writes + 4 b128 reads. Partials: O bf16 + l f32, merged by k_merge.
// -------------------------------------------------------------------------
__global__ __launch_bounds__(256) void k_attn(
    const bf16* __restrict__ Qp, const bf16* __restrict__ Kb,
    const bf16* __restrict__ Vt, bf16* __restrict__ Op, float* __restrict__ lp)
{
  __shared__ __attribute__((aligned(16))) bf16 KVs0[64 * 64];   // K [kpos][d^]
  __shared__ __attribute__((aligned(16))) bf16 KVs1[64 * 64];   // V^T [d][kpos^]
  __shared__ __attribute__((aligned(16))) bf16 Pq[4][32 * 72];  // per-wave P[q][kpos]

  const int tid = threadIdx.x;
  const int w = tid >> 6, lane = tid & 63, quad = lane >> 4, l16 = lane & 15;
  const int bh = blockIdx.x, qb = blockIdx.y, ks = blockIdx.z;
  const int q0 = qb * 128 + w * 32;

  const bf16* Qg = Qp + (size_t)bh * SQQ * HD;
  const bf16* Kg = Kb + (size_t)bh * SEQ * HD;
  const bf16* Vg = Vt + (size_t)bh * HD * SEQ;

  // Q fragments (B-operand): B[d][q] reg j = Qp[q0+qt*16+l16][dk*32+quad*8+j]
  bf16x8 qf[2][2];
#pragma unroll
  for (int qt = 0; qt < 2; ++qt)
#pragma unroll
    for (int dk = 0; dk < 2; ++dk)
      qf[qt][dk] = *(const bf16x8*)&Qg[(size_t)(q0 + qt * 16 + l16) * HD + dk * 32 + quad * 8];

  // swizzled in-row byte offsets for b128 frag reads (loop-invariant)
  const int swz = l16 & 7;
  const int sw0 = ((quad ^ swz) * 16);
  const int sw1 = (((quad + 4) ^ swz) * 16);
  // staging: lane i covers row (i>>3), source chunk (i&7)^(i>>3)
  const int sr = lane >> 3;
  const int sc = (lane & 7) ^ sr;

  f32x4 lac[2] = {};
  f32x4 accO[4][2] = {};
  bf16* PqW = &Pq[w][0];

  for (int it = 0; it < 16; ++it) {
    const int kt = ks * 16 + it;
    __syncthreads();
    if (w < 2) {
      const bf16* src = Kg + (size_t)(kt * 64 + w * 32 + sr) * HD + sc * 8;
      bf16* dst = &KVs0[(w * 32) * 64];
#pragma unroll
      for (int c = 0; c < 4; ++c)
        gload16(src + (size_t)c * 8 * HD, dst + c * 8 * 64);
    } else {
      const bf16* src = Vg + (size_t)((w - 2) * 32 + sr) * SEQ + kt * 64 + sc * 8;
      bf16* dst = &KVs1[((w - 2) * 32) * 64];
#pragma unroll
      for (int c = 0; c < 4; ++c)
        gload16(src + (size_t)c * 8 * SEQ, dst + c * 8 * 64);
    }
    __syncthreads();

    // S^T = K . Q^T : D[row=kpos(quad*4+r), col=q(l16)]
#pragma unroll
    for (int nt = 0; nt < 4; ++nt) {
      const char* rb = (const char*)KVs0 + (nt * 16 + l16) * 128;
      bf16x8 k0 = *(const bf16x8*)(rb + sw0);
      bf16x8 k1 = *(const bf16x8*)(rb + sw1);
#pragma unroll
      for (int qt = 0; qt < 2; ++qt) {
        f32x4 s = {};
        s = MFMA16(k0, qf[qt][0], s, 0, 0, 0);
        s = MFMA16(k1, qf[qt][1], s, 0, 0, 0);
        f32x4 p;
#pragma unroll
        for (int e = 0; e < 4; ++e) p[e] = __builtin_amdgcn_exp2f(s[e]);
        lac[qt] += p;
        bf16x4 pb4;
#pragma unroll
        for (int e = 0; e < 4; ++e) pb4[e] = (bf16)p[e];
        *(bf16x4*)&PqW[(qt * 16 + l16) * 72 + nt * 16 + quad * 4] = pb4;
      }
    }
    __asm__ volatile("s_waitcnt lgkmcnt(0)" ::: "memory");

    // O^T += V^T . P^T : D[row=d(quad*4+r), col=q(l16)]
#pragma unroll
    for (int ck = 0; ck < 2; ++ck) {
      bf16x8 bp0 = *(const bf16x8*)&PqW[(l16) * 72 + ck * 32 + quad * 8];
      bf16x8 bp1 = *(const bf16x8*)&PqW[(16 + l16) * 72 + ck * 32 + quad * 8];
      const int swc = ck ? sw1 : sw0;
#pragma unroll
      for (int dt = 0; dt < 4; ++dt) {
        bf16x8 av = *(const bf16x8*)((const char*)KVs1 + (dt * 16 + l16) * 128 + swc);
        accO[dt][0] = MFMA16(av, bp0, accO[dt][0], 0, 0, 0);
        accO[dt][1] = MFMA16(av, bp1, accO[dt][1], 0, 0, 0);
      }
    }
  }

  // epilogue: partial l (reduced across quads) + partial O (bf16)
#pragma unroll
  for (int qt = 0; qt < 2; ++qt) {
    float lt = lac[qt][0] + lac[qt][1] + lac[qt][2] + lac[qt][3];
    lt += __shfl_xor(lt, 16);
    lt += __shfl_xor(lt, 32);
    if (lane < 16)
      lp[(size_t)(ks * 24 + bh) * SQQ + q0 + qt * 16 + l16] = lt;
#pragma unroll
    for (int dt = 0; dt < 4; ++dt) {
      bf16x4 ov;
#pragma unroll
      for (int r = 0; r < 4; ++r) ov[r] = (bf16)accO[dt][qt][r];
      *(bf16x4*)&Op[((size_t)(ks * 24 + bh) * SQQ + q0 + qt * 16 + l16) * HD + dt * 16 + quad * 4] = ov;
    }
  }
}

// -------------------------------------------------------------------------
// K4: merge 4 K-split partials -> Obb bf16 [b*1024+q][h*64+d]
// -------------------------------------------------------------------------
__global__ __launch_bounds__(256) void k_merge(
    const bf16* __restrict__ Op, const float* __restrict__ lp,
    bf16* __restrict__ Ob)
{
  int t = blockIdx.x * 256 + threadIdx.x;
  int d = t & 63, q = (t >> 6) & 1023, bh = t >> 16;
  float s = 0.f, l = 0.f;
#pragma unroll
  for (int sp = 0; sp < 4; ++sp) {
    s += (float)Op[((size_t)(sp * 24 + bh) * SQQ + q) * HD + d];
    l += lp[(size_t)(sp * 24 + bh) * SQQ + q];
  }
  int b = bh / NH, h = bh - b * NH;
  Ob[((size_t)(b * SQQ + q)) * 384 + h * HD + d] = (bf16)(s / l);
}

// -------------------------------------------------------------------------
// K5: proj GEMM, bf16 MFMA, swapped orientation -> f32x4 stores.
// Obb[4096x384] @ Wpt[384 n][384 k] + bias. Block 128 thr = 2 waves,
// tile 128m x 64n, BK=32, 12 chunks. Grid (32, 6).
// -------------------------------------------------------------------------
__global__ __launch_bounds__(128) void k_proj(
    const bf16* __restrict__ A, const bf16* __restrict__ Wt,
    const float* __restrict__ bias, float* __restrict__ out)
{
  __shared__ __attribute__((aligned(16))) bf16 As[128 * 40];
  __shared__ __attribute__((aligned(16))) bf16 Bs[64 * 40];
  const int tid = threadIdx.x;
  const int w = tid >> 6, lane = tid & 63, quad = lane >> 4, l16 = lane & 15;
  const int m0 = blockIdx.x * 128, n0 = blockIdx.y * 64;

  f32x4 acc[4][4] = {};

  for (int kc = 0; kc < 12; ++kc) {
    const int k0 = kc * 32;
    bf16x8 a4[4], b4[2];
#pragma unroll
    for (int c = 0; c < 4; ++c) {
      int ci = c * 128 + tid, rw = ci >> 2, c8 = ci & 3;
      a4[c] = *(const bf16x8*)&A[(size_t)(m0 + rw) * 384 + k0 + c8 * 8];
    }
#pragma unroll
    for (int c = 0; c < 2; ++c) {
      int ci = c * 128 + tid, rw = ci >> 2, c8 = ci & 3;
      b4[c] = *(const bf16x8*)&Wt[(size_t)(n0 + rw) * 384 + k0 + c8 * 8];
    }
    __syncthreads();
#pragma unroll
    for (int c = 0; c < 4; ++c) {
      int ci = c * 128 + tid, rw = ci >> 2, c8 = ci & 3;
      *(bf16x8*)&As[rw * 40 + c8 * 8] = a4[c];
    }
#pragma unroll
    for (int c = 0; c < 2; ++c) {
      int ci = c * 128 + tid, rw = ci >> 2, c8 = ci & 3;
      *(bf16x8*)&Bs[rw * 40 + c8 * 8] = b4[c];
    }
    __syncthreads();
    bf16x8 af[4], bw[4];
#pragma unroll
    for (int t = 0; t < 4; ++t) {
      af[t] = *(const bf16x8*)&As[(w * 64 + t * 16 + l16) * 40 + quad * 8];
      bw[t] = *(const bf16x8*)&Bs[(t * 16 + l16) * 40 + quad * 8];
    }
#pragma unroll
    for (int mt = 0; mt < 4; ++mt)
#pragma unroll
      for (int nt = 0; nt < 4; ++nt)
        acc[mt][nt] = MFMA16(bw[nt], af[mt], acc[mt][nt], 0, 0, 0);
  }

  f32x4 bv[4];
#pragma unroll
  for (int nt = 0; nt < 4; ++nt)
    bv[nt] = *(const f32x4*)&bias[n0 + nt * 16 + quad * 4];
#pragma unroll
  for (int mt = 0; mt < 4; ++mt) {
    int m = m0 + w * 64 + mt * 16 + l16;
#pragma unroll
    for (int nt = 0; nt < 4; ++nt) {
      f32x4 o = acc[mt][nt] + bv[nt];
      *(f32x4*)&out[(size_t)m * 384 + n0 + nt * 16 + quad * 4] = o;
    }
  }
}

// -------------------------------------------------------------------------
// ws layout (bytes):                                         size
//   Qb bf16 16384*384  /  Opart bf16 [4][24][1024][64]  @ 0   12582912 (overlaid)
//   Kb  bf16 24*4096*64   @ 12582912                          12582912
//   Vt  bf16 24*64*4096   @ 25165824                          12582912
//   Qp  bf16 24*1024*64   @ 37748736                           3145728
//   Wqt bf16 1152*192     @ 40894464                            442368
//   Wpt bf16 384*384      @ 41336832                            294912
//   lp  f32  4*24*1024    @ 41631744                            393216
//   Obb bf16 4096*384     @ 42024960                           3145728
// total 45170688 (< 47185920 used successfully in R1)
// -------------------------------------------------------------------------
extern "C" void kernel_launch(void* const* d_in, const int* in_sizes, int n_in,
                              void* d_out, int out_size, void* d_ws, size_t ws_size,
                              hipStream_t stream)
{
  (void)in_sizes; (void)n_in; (void)out_size; (void)ws_size;
  const float* X  = (const float*)d_in[0];
  const float* Wq = (const float*)d_in[1];
  const float* qb = (const float*)d_in[2];
  const float* Wp = (const float*)d_in[3];
  const float* pb = (const float*)d_in[4];
  float* out = (float*)d_out;

  char* ws = (char*)d_ws;
  bf16*  Qb    = (bf16*)(ws);
  bf16*  Opart = (bf16*)(ws);                // overlays Qb (dead after k_pool)
  bf16*  Kb    = (bf16*)(ws + 12582912);
  bf16*  Vt    = (bf16*)(ws + 25165824);
  bf16*  Qp    = (bf16*)(ws + 37748736);
  bf16*  Wqt   = (bf16*)(ws + 40894464);
  bf16*  Wpt   = (bf16*)(ws + 41336832);
  float* lpart = (float*)(ws + 41631744);
  bf16*  Obb   = (bf16*)(ws + 42024960);

  k_prep <<<1440, 256, 0, stream>>>(Wq, Wp, Wqt, Wpt);
  k_qkv  <<<dim3(128, 9), 256, 0, stream>>>(X, Wqt, qb, Qb, Kb, Vt);
  k_pool <<<6144, 256, 0, stream>>>(Qb, Qp);
  k_attn <<<dim3(24, 8, 4), 256, 0, stream>>>(Qp, Kb, Vt, Opart, lpart);
  k_merge<<<6144, 256, 0, stream>>>(Opart, lpart, Obb);
  k_proj <<<dim3(32, 6), 128, 0, stream>>>(Obb, Wpt, pb, out);
}

// Round 3
// 162.091 us; speedup vs baseline: 1.9747x; 1.0402x over previous
//
#include <hip/hip_runtime.h>

typedef __bf16 bf16;
typedef bf16 bf16x8 __attribute__((ext_vector_type(8)));
typedef bf16 bf16x4 __attribute__((ext_vector_type(4)));
typedef float f32x4 __attribute__((ext_vector_type(4)));

#define SEQ 4096
#define SQQ 1024
#define NH  6
#define HD  64

#define MFMA16 __builtin_amdgcn_mfma_f32_16x16x32_bf16

typedef const __attribute__((address_space(1))) void gvoid_t;
typedef __attribute__((address_space(3))) void svoid_t;

__device__ __forceinline__ void gload16(const bf16* g, bf16* l) {
  __builtin_amdgcn_global_load_lds((gvoid_t*)g, (svoid_t*)l, 16, 0, 0);
}

// -------------------------------------------------------------------------
// K0: prep — Wq [192][1152] -> Wqt bf16 [1152 n][192 k];
//            Wp [384][384]  -> Wpt bf16 [384 n][384 k];
//            X f32 -> Xb bf16 (elementwise, vec4)
// -------------------------------------------------------------------------
__global__ __launch_bounds__(256) void k_prep(
    const float* __restrict__ X, const float* __restrict__ Wq,
    const float* __restrict__ Wp,
    bf16* __restrict__ Xb, bf16* __restrict__ Wqt, bf16* __restrict__ Wpt)
{
  int i = blockIdx.x * 256 + threadIdx.x;
  if (i < 1152 * 192) {
    int n = i / 192, k = i - n * 192;
    Wqt[i] = (bf16)Wq[k * 1152 + n];
  } else if (i < 1152 * 192 + 384 * 384) {
    int j = i - 1152 * 192;
    int n = j / 384, k = j - n * 384;
    Wpt[j] = (bf16)Wp[k * 384 + n];
  } else {
    int v = i - (1152 * 192 + 384 * 384);
    if (v < 786432) {
      f32x4 x = *(const f32x4*)&X[(size_t)v * 4];
      bf16x4 h;
#pragma unroll
      for (int e = 0; e < 4; ++e) h[e] = (bf16)x[e];
      *(bf16x4*)&Xb[(size_t)v * 4] = h;
    }
  }
}

// -------------------------------------------------------------------------
// K1: QKV GEMM, bf16 MFMA, NO LDS staging: fragments loaded directly from
// global (A-tile is L2-local: same-m blocks land on one XCD since gridX=128
// and 128%8==0). 2-deep ping-pong, zero barriers in main loop.
// Block 256 thr = 4 waves (2x2), tile 128x128, wave tile 64x64, 6 k-chunks.
// Epilogue: c3==2 (V) normal orientation -> V^T b64 stores;
//           c3==1 (K) swapped -> b64 stores;
//           c3==0 (Q) swapped -> LDS tile -> fused 2x2 max-pool -> Qp
//           (scale 0.125*log2e folded; m-block = one H-row pair).
// -------------------------------------------------------------------------
__global__ __launch_bounds__(256) void k_qkv(
    const bf16* __restrict__ Xb, const bf16* __restrict__ Wt,
    const float* __restrict__ bias,
    bf16* __restrict__ Kb, bf16* __restrict__ Vt, bf16* __restrict__ Qp)
{
  __shared__ __attribute__((aligned(16))) bf16 Qs[128 * 136];
  const int tid = threadIdx.x;
  const int w = tid >> 6, lane = tid & 63, quad = lane >> 4, l16 = lane & 15;
  const int wm = w & 1, wn = w >> 1;
  const int m0 = blockIdx.x * 128, n0 = blockIdx.y * 128;
  const int c3 = n0 / 384, nb = n0 - c3 * 384, b = m0 >> 12;

  const bf16* Arow = Xb + (size_t)(m0 + wm * 64 + l16) * 192 + quad * 8;
  const bf16* Brow = Wt + (size_t)(n0 + wn * 64 + l16) * 192 + quad * 8;

  f32x4 acc[4][4] = {};
  bf16x8 afA[4], bwA[4], afB[4], bwB[4];
#pragma unroll
  for (int t = 0; t < 4; ++t) {
    afA[t] = *(const bf16x8*)(Arow + t * 16 * 192);
    bwA[t] = *(const bf16x8*)(Brow + t * 16 * 192);
  }
#pragma unroll
  for (int kk = 0; kk < 6; ++kk) {
    bf16x8* af  = (kk & 1) ? afB : afA;
    bf16x8* bw  = (kk & 1) ? bwB : bwA;
    bf16x8* afn = (kk & 1) ? afA : afB;
    bf16x8* bwn = (kk & 1) ? bwA : bwB;
    if (kk < 5) {
      const int ko = (kk + 1) * 32;
#pragma unroll
      for (int t = 0; t < 4; ++t) {
        afn[t] = *(const bf16x8*)(Arow + t * 16 * 192 + ko);
        bwn[t] = *(const bf16x8*)(Brow + t * 16 * 192 + ko);
      }
    }
    if (c3 == 2) {
#pragma unroll
      for (int mt = 0; mt < 4; ++mt)
#pragma unroll
        for (int nt = 0; nt < 4; ++nt)
          acc[mt][nt] = MFMA16(af[mt], bw[nt], acc[mt][nt], 0, 0, 0);
    } else {
#pragma unroll
      for (int mt = 0; mt < 4; ++mt)
#pragma unroll
        for (int nt = 0; nt < 4; ++nt)
          acc[mt][nt] = MFMA16(bw[nt], af[mt], acc[mt][nt], 0, 0, 0);
    }
  }

  if (c3 == 2) {
    // normal: D[row=m=s (quad*4+r)][col=n (l16)] -> V^T[d][s] b64 stores
    float bn[4];
#pragma unroll
    for (int nt = 0; nt < 4; ++nt) bn[nt] = bias[n0 + wn * 64 + nt * 16 + l16];
#pragma unroll
    for (int mt = 0; mt < 4; ++mt) {
      int sb = (m0 & 4095) + wm * 64 + mt * 16 + quad * 4;
#pragma unroll
      for (int nt = 0; nt < 4; ++nt) {
        int dcol = nb + wn * 64 + nt * 16 + l16;
        int h = dcol >> 6, dd = dcol & 63;
        bf16x4 pv;
#pragma unroll
        for (int r = 0; r < 4; ++r) pv[r] = (bf16)(acc[mt][nt][r] + bn[nt]);
        *(bf16x4*)&Vt[((size_t)(b * NH + h) * HD + dd) * SEQ + sb] = pv;
      }
    }
  } else if (c3 == 1) {
    // swapped: D[row=n (quad*4+r)][col=m (l16)] -> K[bh][s][d] b64 stores
    f32x4 bv[4];
#pragma unroll
    for (int nt = 0; nt < 4; ++nt)
      bv[nt] = *(const f32x4*)&bias[n0 + wn * 64 + nt * 16 + quad * 4];
#pragma unroll
    for (int mt = 0; mt < 4; ++mt) {
      int s = (m0 & 4095) + wm * 64 + mt * 16 + l16;
#pragma unroll
      for (int nt = 0; nt < 4; ++nt) {
        int ncol = nb + wn * 64 + nt * 16 + quad * 4;
        int h = ncol >> 6, dd = ncol & 63;
        bf16x4 pv;
#pragma unroll
        for (int r = 0; r < 4; ++r) pv[r] = (bf16)(acc[mt][nt][r] + bv[nt][r]);
        *(bf16x4*)&Kb[((size_t)(b * NH + h) * SEQ + s) * HD + dd] = pv;
      }
    }
  } else {
    // Q: swapped -> LDS tile -> fused 2x2 max-pool -> Qp
    f32x4 bv[4];
#pragma unroll
    for (int nt = 0; nt < 4; ++nt)
      bv[nt] = *(const f32x4*)&bias[n0 + wn * 64 + nt * 16 + quad * 4];
#pragma unroll
    for (int mt = 0; mt < 4; ++mt) {
      int ml = wm * 64 + mt * 16 + l16;
#pragma unroll
      for (int nt = 0; nt < 4; ++nt) {
        int ncl = wn * 64 + nt * 16 + quad * 4;
        bf16x4 pv;
#pragma unroll
        for (int r = 0; r < 4; ++r) pv[r] = (bf16)(acc[mt][nt][r] + bv[nt][r]);
        *(bf16x4*)&Qs[ml * 136 + ncl] = pv;
      }
    }
    __syncthreads();
    // pool: thread t -> wq = t>>3 (32), col-group cg = t&7 (16 cols each)
    const int wq = tid >> 3, cg = tid & 7;
    const int hq = (m0 & 4095) >> 7;
#pragma unroll
    for (int j8 = 0; j8 < 2; ++j8) {
      int co = cg * 16 + j8 * 8;
      bf16x8 q0 = *(const bf16x8*)&Qs[(2 * wq)     * 136 + co];
      bf16x8 q1 = *(const bf16x8*)&Qs[(2 * wq + 1) * 136 + co];
      bf16x8 q2 = *(const bf16x8*)&Qs[(64 + 2 * wq)     * 136 + co];
      bf16x8 q3 = *(const bf16x8*)&Qs[(64 + 2 * wq + 1) * 136 + co];
      bf16x8 o;
#pragma unroll
      for (int e = 0; e < 8; ++e) {
        float mx = fmaxf(fmaxf((float)q0[e], (float)q1[e]),
                         fmaxf((float)q2[e], (float)q3[e]));
        o[e] = (bf16)(mx * 0.180336880111f);   // 0.125 * log2(e)
      }
      int gc = nb + co;
      int h = gc >> 6, d0 = gc & 63;
      *(bf16x8*)&Qp[((size_t)(b * NH + h) * SQQ + hq * 32 + wq) * HD + d0] = o;
    }
  }
}

// -------------------------------------------------------------------------
// K3: attention, S^T formulation, no max-stabilization (|logit|<~13, safe).
// Grid (bh=24, qblk=8, ksplit=4); 256 thr = 4 waves, 32 q/wave, K-tile 64.
// (unchanged from R2 — passed, left the top-5)
// -------------------------------------------------------------------------
__global__ __launch_bounds__(256) void k_attn(
    const bf16* __restrict__ Qp, const bf16* __restrict__ Kb,
    const bf16* __restrict__ Vt, bf16* __restrict__ Op, float* __restrict__ lp)
{
  __shared__ __attribute__((aligned(16))) bf16 KVs0[64 * 64];   // K [kpos][d^]
  __shared__ __attribute__((aligned(16))) bf16 KVs1[64 * 64];   // V^T [d][kpos^]
  __shared__ __attribute__((aligned(16))) bf16 Pq[4][32 * 72];  // per-wave P[q][kpos]

  const int tid = threadIdx.x;
  const int w = tid >> 6, lane = tid & 63, quad = lane >> 4, l16 = lane & 15;
  const int bh = blockIdx.x, qb = blockIdx.y, ks = blockIdx.z;
  const int q0 = qb * 128 + w * 32;

  const bf16* Qg = Qp + (size_t)bh * SQQ * HD;
  const bf16* Kg = Kb + (size_t)bh * SEQ * HD;
  const bf16* Vg = Vt + (size_t)bh * HD * SEQ;

  bf16x8 qf[2][2];
#pragma unroll
  for (int qt = 0; qt < 2; ++qt)
#pragma unroll
    for (int dk = 0; dk < 2; ++dk)
      qf[qt][dk] = *(const bf16x8*)&Qg[(size_t)(q0 + qt * 16 + l16) * HD + dk * 32 + quad * 8];

  const int swz = l16 & 7;
  const int sw0 = ((quad ^ swz) * 16);
  const int sw1 = (((quad + 4) ^ swz) * 16);
  const int sr = lane >> 3;
  const int sc = (lane & 7) ^ sr;

  f32x4 lac[2] = {};
  f32x4 accO[4][2] = {};
  bf16* PqW = &Pq[w][0];

  for (int it = 0; it < 16; ++it) {
    const int kt = ks * 16 + it;
    __syncthreads();
    if (w < 2) {
      const bf16* src = Kg + (size_t)(kt * 64 + w * 32 + sr) * HD + sc * 8;
      bf16* dst = &KVs0[(w * 32) * 64];
#pragma unroll
      for (int c = 0; c < 4; ++c)
        gload16(src + (size_t)c * 8 * HD, dst + c * 8 * 64);
    } else {
      const bf16* src = Vg + (size_t)((w - 2) * 32 + sr) * SEQ + kt * 64 + sc * 8;
      bf16* dst = &KVs1[((w - 2) * 32) * 64];
#pragma unroll
      for (int c = 0; c < 4; ++c)
        gload16(src + (size_t)c * 8 * SEQ, dst + c * 8 * 64);
    }
    __syncthreads();

#pragma unroll
    for (int nt = 0; nt < 4; ++nt) {
      const char* rb = (const char*)KVs0 + (nt * 16 + l16) * 128;
      bf16x8 k0 = *(const bf16x8*)(rb + sw0);
      bf16x8 k1 = *(const bf16x8*)(rb + sw1);
#pragma unroll
      for (int qt = 0; qt < 2; ++qt) {
        f32x4 s = {};
        s = MFMA16(k0, qf[qt][0], s, 0, 0, 0);
        s = MFMA16(k1, qf[qt][1], s, 0, 0, 0);
        f32x4 p;
#pragma unroll
        for (int e = 0; e < 4; ++e) p[e] = __builtin_amdgcn_exp2f(s[e]);
        lac[qt] += p;
        bf16x4 pb4;
#pragma unroll
        for (int e = 0; e < 4; ++e) pb4[e] = (bf16)p[e];
        *(bf16x4*)&PqW[(qt * 16 + l16) * 72 + nt * 16 + quad * 4] = pb4;
      }
    }
    __asm__ volatile("s_waitcnt lgkmcnt(0)" ::: "memory");

#pragma unroll
    for (int ck = 0; ck < 2; ++ck) {
      bf16x8 bp0 = *(const bf16x8*)&PqW[(l16) * 72 + ck * 32 + quad * 8];
      bf16x8 bp1 = *(const bf16x8*)&PqW[(16 + l16) * 72 + ck * 32 + quad * 8];
      const int swc = ck ? sw1 : sw0;
#pragma unroll
      for (int dt = 0; dt < 4; ++dt) {
        bf16x8 av = *(const bf16x8*)((const char*)KVs1 + (dt * 16 + l16) * 128 + swc);
        accO[dt][0] = MFMA16(av, bp0, accO[dt][0], 0, 0, 0);
        accO[dt][1] = MFMA16(av, bp1, accO[dt][1], 0, 0, 0);
      }
    }
  }

#pragma unroll
  for (int qt = 0; qt < 2; ++qt) {
    float lt = lac[qt][0] + lac[qt][1] + lac[qt][2] + lac[qt][3];
    lt += __shfl_xor(lt, 16);
    lt += __shfl_xor(lt, 32);
    if (lane < 16)
      lp[(size_t)(ks * 24 + bh) * SQQ + q0 + qt * 16 + l16] = lt;
#pragma unroll
    for (int dt = 0; dt < 4; ++dt) {
      bf16x4 ov;
#pragma unroll
      for (int r = 0; r < 4; ++r) ov[r] = (bf16)accO[dt][qt][r];
      *(bf16x4*)&Op[((size_t)(ks * 24 + bh) * SQQ + q0 + qt * 16 + l16) * HD + dt * 16 + quad * 4] = ov;
    }
  }
}

// -------------------------------------------------------------------------
// K4: merge 4 K-split partials -> Obb bf16 [b*1024+q][h*64+d], vec8
// -------------------------------------------------------------------------
__global__ __launch_bounds__(256) void k_merge(
    const bf16* __restrict__ Op, const float* __restrict__ lp,
    bf16* __restrict__ Ob)
{
  int t = blockIdx.x * 256 + threadIdx.x;          // 196608 total
  int d8 = t & 7, q = (t >> 3) & 1023, bh = t >> 13;
  float l = 0.f;
  float s[8] = {};
#pragma unroll
  for (int sp = 0; sp < 4; ++sp) {
    l += lp[(size_t)(sp * 24 + bh) * SQQ + q];
    bf16x8 v = *(const bf16x8*)&Op[((size_t)(sp * 24 + bh) * SQQ + q) * HD + d8 * 8];
#pragma unroll
    for (int e = 0; e < 8; ++e) s[e] += (float)v[e];
  }
  float inv = 1.0f / l;
  int b = bh / NH, h = bh - b * NH;
  bf16x8 o;
#pragma unroll
  for (int e = 0; e < 8; ++e) o[e] = (bf16)(s[e] * inv);
  *(bf16x8*)&Ob[((size_t)(b * SQQ + q)) * 384 + h * HD + d8 * 8] = o;
}

// -------------------------------------------------------------------------
// K5: proj GEMM, bf16 MFMA, swapped orientation -> f32x4 stores.
// Obb[4096x384] @ Wpt[384 n][384 k] + bias. Grid (32, 6), 128 thr.
// -------------------------------------------------------------------------
__global__ __launch_bounds__(128) void k_proj(
    const bf16* __restrict__ A, const bf16* __restrict__ Wt,
    const float* __restrict__ bias, float* __restrict__ out)
{
  __shared__ __attribute__((aligned(16))) bf16 As[128 * 40];
  __shared__ __attribute__((aligned(16))) bf16 Bs[64 * 40];
  const int tid = threadIdx.x;
  const int w = tid >> 6, lane = tid & 63, quad = lane >> 4, l16 = lane & 15;
  const int m0 = blockIdx.x * 128, n0 = blockIdx.y * 64;

  f32x4 acc[4][4] = {};

  for (int kc = 0; kc < 12; ++kc) {
    const int k0 = kc * 32;
    bf16x8 a4[4], b4[2];
#pragma unroll
    for (int c = 0; c < 4; ++c) {
      int ci = c * 128 + tid, rw = ci >> 2, c8 = ci & 3;
      a4[c] = *(const bf16x8*)&A[(size_t)(m0 + rw) * 384 + k0 + c8 * 8];
    }
#pragma unroll
    for (int c = 0; c < 2; ++c) {
      int ci = c * 128 + tid, rw = ci >> 2, c8 = ci & 3;
      b4[c] = *(const bf16x8*)&Wt[(size_t)(n0 + rw) * 384 + k0 + c8 * 8];
    }
    __syncthreads();
#pragma unroll
    for (int c = 0; c < 4; ++c) {
      int ci = c * 128 + tid, rw = ci >> 2, c8 = ci & 3;
      *(bf16x8*)&As[rw * 40 + c8 * 8] = a4[c];
    }
#pragma unroll
    for (int c = 0; c < 2; ++c) {
      int ci = c * 128 + tid, rw = ci >> 2, c8 = ci & 3;
      *(bf16x8*)&Bs[rw * 40 + c8 * 8] = b4[c];
    }
    __syncthreads();
    bf16x8 af[4], bw[4];
#pragma unroll
    for (int t = 0; t < 4; ++t) {
      af[t] = *(const bf16x8*)&As[(w * 64 + t * 16 + l16) * 40 + quad * 8];
      bw[t] = *(const bf16x8*)&Bs[(t * 16 + l16) * 40 + quad * 8];
    }
#pragma unroll
    for (int mt = 0; mt < 4; ++mt)
#pragma unroll
      for (int nt = 0; nt < 4; ++nt)
        acc[mt][nt] = MFMA16(bw[nt], af[mt], acc[mt][nt], 0, 0, 0);
  }

  f32x4 bv[4];
#pragma unroll
  for (int nt = 0; nt < 4; ++nt)
    bv[nt] = *(const f32x4*)&bias[n0 + nt * 16 + quad * 4];
#pragma unroll
  for (int mt = 0; mt < 4; ++mt) {
    int m = m0 + w * 64 + mt * 16 + l16;
#pragma unroll
    for (int nt = 0; nt < 4; ++nt) {
      f32x4 o = acc[mt][nt] + bv[nt];
      *(f32x4*)&out[(size_t)m * 384 + n0 + nt * 16 + quad * 4] = o;
    }
  }
}

// -------------------------------------------------------------------------
// ws layout (bytes):
//   Kb    @ 0         12582912   (qkv -> attn)
//   Vt    @ 12582912  12582912   (qkv -> attn)
//   Qp    @ 25165824   3145728   (qkv -> attn)
//   Wqt   @ 28311552    442368   (prep -> qkv)
//   Wpt   @ 28753920    294912   (prep -> proj)
//   lp    @ 29048832    393216   (attn -> merge)
//   Obb   @ 29442048   3145728   (merge -> proj)
//   Xb    @ 32587776   6291456   (prep -> qkv, dead after)
//   Opart @ 32587776  12582912   (attn -> merge; overlays Xb)
// total 45170688  (<= 47185920 proven safe in R1)
// -------------------------------------------------------------------------
extern "C" void kernel_launch(void* const* d_in, const int* in_sizes, int n_in,
                              void* d_out, int out_size, void* d_ws, size_t ws_size,
                              hipStream_t stream)
{
  (void)in_sizes; (void)n_in; (void)out_size; (void)ws_size;
  const float* X  = (const float*)d_in[0];
  const float* Wq = (const float*)d_in[1];
  const float* qb = (const float*)d_in[2];
  const float* Wp = (const float*)d_in[3];
  const float* pb = (const float*)d_in[4];
  float* out = (float*)d_out;

  char* ws = (char*)d_ws;
  bf16*  Kb    = (bf16*)(ws);
  bf16*  Vt    = (bf16*)(ws + 12582912);
  bf16*  Qp    = (bf16*)(ws + 25165824);
  bf16*  Wqt   = (bf16*)(ws + 28311552);
  bf16*  Wpt   = (bf16*)(ws + 28753920);
  float* lpart = (float*)(ws + 29048832);
  bf16*  Obb   = (bf16*)(ws + 29442048);
  bf16*  Xb    = (bf16*)(ws + 32587776);
  bf16*  Opart = (bf16*)(ws + 32587776);   // overlays Xb (dead after k_qkv)

  k_prep <<<4512, 256, 0, stream>>>(X, Wq, Wp, Xb, Wqt, Wpt);
  k_qkv  <<<dim3(128, 9), 256, 0, stream>>>(Xb, Wqt, qb, Kb, Vt, Qp);
  k_attn <<<dim3(24, 8, 4), 256, 0, stream>>>(Qp, Kb, Vt, Opart, lpart);
  k_merge<<<768, 256, 0, stream>>>(Opart, lpart, Obb);
  k_proj <<<dim3(32, 6), 128, 0, stream>>>(Obb, Wpt, pb, out);
}